// Round 2
// baseline (861.558 us; speedup 1.0000x reference)
//
#include <hip/hip_runtime.h>

typedef unsigned short u16;
typedef __attribute__((ext_vector_type(8))) short bfrag;     // 8 bf16 (4 VGPRs) MFMA A/B
typedef __attribute__((ext_vector_type(4))) float ffrag;     // 4 f32 MFMA C/D
typedef __attribute__((ext_vector_type(4))) float f4;
typedef __attribute__((ext_vector_type(4))) unsigned short u16x4;

#define NVERT 35709
#define NFACE 70789
#define NV3   107127
#define NB    128

// ---- workspace byte layout (total ~154.8 MB) ----
#define SHAPE_OFF 0ull            // f32, NB*NV3            (54,849,024 B)
#define TEX_OFF   54849024ull     // u16 bf16, NB*NV3       (27,424,512 B)
#define FN_OFF    82273536ull     // u16 bf16, NB*NFACE*4   (72,487,936 B) xyz+pad
#define CPACK_OFF 154761472ull    // u16 bf16, NB*256 padded coeffs [id80|0*16|ex64|tex80|0*16]
#define ROT_OFF   154827008ull    // f32, NB*9  (M[d][c], M = Rz@Ry@Rx)
#define G_OFF     154831616ull    // f32, NB*27 (G[c][d] = gamma[d*9+c] + 0.8*(c==0))
#define TRANS_OFF 154845440ull    // f32, NB*3
#define MEAN_OFF  154846976ull    // f32, 3

// ---- output element offsets (f32 out) ----
#define LMS_BASE  13712256ull     // after face_color (B*NV*3)
#define ST_BASE   13729664ull     // after lms (B*68*2)

__device__ __forceinline__ float b2f(u16 s) {
  union { unsigned u; float f; } v; v.u = ((unsigned)s) << 16; return v.f;
}
__device__ __forceinline__ u16 f2b(float x) {  // f32 -> bf16 RNE
  union { float f; unsigned u; } v; v.f = x;
  unsigned r = v.u + 0x7FFFu + ((v.u >> 16) & 1u);
  return (u16)(r >> 16);
}
__device__ __forceinline__ bfrag cvt8(const float* p) {  // 8 f32 -> 8 bf16 (two f4 loads)
  f4 a = *(const f4*)p;
  f4 b = *(const f4*)(p + 4);
  bfrag r;
  r[0] = (short)f2b(a.x); r[1] = (short)f2b(a.y); r[2] = (short)f2b(a.z); r[3] = (short)f2b(a.w);
  r[4] = (short)f2b(b.x); r[5] = (short)f2b(b.y); r[6] = (short)f2b(b.z); r[7] = (short)f2b(b.w);
  return r;
}

// K0: mean of meanshape over vertices (3 values)
__global__ __launch_bounds__(256) void k_mean(const float* __restrict__ ms, float* __restrict__ mean) {
  __shared__ float s[3];
  if (threadIdx.x < 3) s[threadIdx.x] = 0.f;
  __syncthreads();
  float a0 = 0.f, a1 = 0.f, a2 = 0.f;
  for (int v = threadIdx.x; v < NVERT; v += 256) {
    a0 += ms[v * 3 + 0];
    a1 += ms[v * 3 + 1];
    a2 += ms[v * 3 + 2];
  }
  atomicAdd(&s[0], a0); atomicAdd(&s[1], a1); atomicAdd(&s[2], a2);
  __syncthreads();
  if (threadIdx.x < 3) mean[threadIdx.x] = s[threadIdx.x] * (1.0f / (float)NVERT);
}

// K1: per-batch params: bf16-packed coeffs, rotation M = Rz@Ry@Rx (row-major M[d][c]),
//     G[c][d] (gamma transposed, +0.8 on c==0), trans.
__global__ __launch_bounds__(128) void k_params(const float* __restrict__ coeff, u16* __restrict__ cpack,
                                                float* __restrict__ rot, float* __restrict__ G,
                                                float* __restrict__ tr) {
  int b = threadIdx.x;
  const float* c = coeff + b * 257;
  u16* cp = cpack + b * 256;
  for (int k = 0; k < 80; k++) cp[k] = f2b(c[k]);            // id
  for (int k = 80; k < 96; k++) cp[k] = 0;                   // pad
  for (int k = 0; k < 64; k++) cp[96 + k] = f2b(c[80 + k]);  // ex
  for (int k = 0; k < 80; k++) cp[160 + k] = f2b(c[144 + k]);// tex
  for (int k = 240; k < 256; k++) cp[k] = 0;                 // pad
  float ax = c[224], ay = c[225], az = c[226];
  float sx = sinf(ax), cx = cosf(ax);
  float sy = sinf(ay), cy = cosf(ay);
  float sz = sinf(az), cz = cosf(az);
  float* M = rot + b * 9;
  M[0] = cz * cy;  M[1] = cz * sy * sx - sz * cx;  M[2] = sz * sx + cz * sy * cx;
  M[3] = sz * cy;  M[4] = cz * cx + sz * sy * sx;  M[5] = sz * sy * cx - cz * sx;
  M[6] = -sy;      M[7] = cy * sx;                 M[8] = cy * cx;
  float* g = G + b * 27;
  for (int cc = 0; cc < 9; cc++)
    for (int d = 0; d < 3; d++)
      g[cc * 3 + d] = c[227 + d * 9 + cc] + (cc == 0 ? 0.8f : 0.0f);
  float* t = tr + b * 3;
  t[0] = c[254]; t[1] = c[255]; t[2] = c[256];
}

// K2: MFMA GEMM, f32 bases converted to bf16 in-register. D[b][j] = sum_k coeff[b][k]*base[j][k].
// Each wave owns one 16-wide j tile, loads B frags once, loops all 8 batch tiles of 16.
__global__ __launch_bounds__(256) void k_gemm(const float* __restrict__ idB, const float* __restrict__ exB,
                                              const float* __restrict__ txB, const float* __restrict__ ms,
                                              const float* __restrict__ mt, const u16* __restrict__ cpack,
                                              const float* __restrict__ meanc,
                                              float* __restrict__ shp, u16* __restrict__ texo) {
  int wave = threadIdx.x >> 6, lane = threadIdx.x & 63;
  int jt = blockIdx.x * 4 + wave;
  int col = lane & 15, quad = lane >> 4;
  int j = jt * 16 + col;
  bool jv = (j < NV3);
  int jc = jv ? j : (NV3 - 1);                 // clamped: loads always in-bounds
  bfrag z8 = {0, 0, 0, 0, 0, 0, 0, 0};
  bfrag bid[3], bex[2], btx[3];
  const float* rowI = idB + (size_t)jc * 80;
  const float* rowT = txB + (size_t)jc * 80;
  const float* rowE = exB + (size_t)jc * 64;
#pragma unroll
  for (int f = 0; f < 3; f++) {
    int k = f * 32 + quad * 8;
    bool ok = (k < 80);
    int ks = ok ? k : 0;                       // clamped address, select value
    bfrag vi = cvt8(rowI + ks);
    bfrag vt = cvt8(rowT + ks);
    bid[f] = ok ? vi : z8;
    btx[f] = ok ? vt : z8;
  }
#pragma unroll
  for (int f = 0; f < 2; f++) {
    int k = f * 32 + quad * 8;                 // <= 56, always in-bounds
    bex[f] = cvt8(rowE + k);
  }
  float msj = ms[jc];
  float mtj = mt[jc];
  float mc = meanc[jc % 3];

  for (int bt = 0; bt < 8; bt++) {
    const u16* cp = cpack + (size_t)(bt * 16 + col) * 256;  // A: m=lane&15, k=quad*8+i
    ffrag accS = {0.f, 0.f, 0.f, 0.f};
    ffrag accT = {0.f, 0.f, 0.f, 0.f};
#pragma unroll
    for (int f = 0; f < 3; f++) {
      bfrag a = *(const bfrag*)(cp + f * 32 + quad * 8);
      accS = __builtin_amdgcn_mfma_f32_16x16x32_bf16(a, bid[f], accS, 0, 0, 0);
    }
#pragma unroll
    for (int f = 0; f < 2; f++) {
      bfrag a = *(const bfrag*)(cp + 96 + f * 32 + quad * 8);
      accS = __builtin_amdgcn_mfma_f32_16x16x32_bf16(a, bex[f], accS, 0, 0, 0);
    }
#pragma unroll
    for (int f = 0; f < 3; f++) {
      bfrag a = *(const bfrag*)(cp + 160 + f * 32 + quad * 8);
      accT = __builtin_amdgcn_mfma_f32_16x16x32_bf16(a, btx[f], accT, 0, 0, 0);
    }
    if (jv) {
#pragma unroll
      for (int r = 0; r < 4; r++) {
        int br = bt * 16 + quad * 4 + r;       // C/D: col=lane&15, row=quad*4+reg
        size_t o = (size_t)br * NV3 + j;
        shp[o] = accS[r] + msj - mc;
        texo[o] = f2b(accT[r] + mtj);
      }
    }
  }
}

// K3: face normals fn = cross(v1-v2, v2-v3), stored bf16 xyz+pad (8B aligned)
__global__ __launch_bounds__(256) void k_fn(const float* __restrict__ shp, const int* __restrict__ tri,
                                            u16* __restrict__ fnw) {
  int f = blockIdx.x * 256 + threadIdx.x;
  int b = blockIdx.y;
  if (f >= NFACE) return;
  int i0 = tri[f * 3 + 0] - 1, i1 = tri[f * 3 + 1] - 1, i2 = tri[f * 3 + 2] - 1;
  const float* s = shp + (size_t)b * NV3;
  float x1 = s[i0 * 3], y1 = s[i0 * 3 + 1], z1 = s[i0 * 3 + 2];
  float x2 = s[i1 * 3], y2 = s[i1 * 3 + 1], z2 = s[i1 * 3 + 2];
  float x3 = s[i2 * 3], y3 = s[i2 * 3 + 1], z3 = s[i2 * 3 + 2];
  float e1x = x1 - x2, e1y = y1 - y2, e1z = z1 - z2;
  float e2x = x2 - x3, e2y = y2 - y3, e2z = z2 - z3;
  float fx = e1y * e2z - e1z * e2y;
  float fy = e1z * e2x - e1x * e2z;
  float fz = e1x * e2y - e1y * e2x;
  u16x4 st; st.x = f2b(fx); st.y = f2b(fy); st.z = f2b(fz); st.w = 0;
  *(u16x4*)(fnw + ((size_t)b * NFACE + f) * 4) = st;
}

// K4: vn = sum of 8 gathered fn (index NFACE -> zero row), normalize, rotate; illuminate tex;
//     write face_color and shape_t (f32 out).
__global__ __launch_bounds__(256) void k_final(const float* __restrict__ shp, const u16* __restrict__ texb,
                                               const u16* __restrict__ fnw, const int* __restrict__ pbuf,
                                               const float* __restrict__ rot, const float* __restrict__ G,
                                               const float* __restrict__ tr, float* __restrict__ out) {
  int v = blockIdx.x * 256 + threadIdx.x;
  int b = blockIdx.y;
  if (v >= NVERT) return;
  const int* p = pbuf + (size_t)v * 8;
  float vx = 0.f, vy = 0.f, vz = 0.f;
#pragma unroll
  for (int i = 0; i < 8; i++) {
    int id = p[i] - 1;                 // in [0, NFACE]; NFACE == appended zero row
    if (id < NFACE) {
      u16x4 q = *(const u16x4*)(fnw + ((size_t)b * NFACE + id) * 4);
      vx += b2f(q.x); vy += b2f(q.y); vz += b2f(q.z);
    }
  }
  float n2 = vx * vx + vy * vy + vz * vz;
  float inv = rsqrtf(fmaxf(n2, 1e-30f));
  vx *= inv; vy *= inv; vz *= inv;
  const float* M = rot + b * 9;
  float nx = vx * M[0] + vy * M[1] + vz * M[2];
  float ny = vx * M[3] + vy * M[4] + vz * M[5];
  float nz = vx * M[6] + vy * M[7] + vz * M[8];
  const float* sp = shp + (size_t)b * NV3 + (size_t)v * 3;
  float sx = sp[0], sy = sp[1], sz = sp[2];
  const float* T = tr + b * 3;
  float ox = sx * M[0] + sy * M[1] + sz * M[2] + T[0];
  float oy = sx * M[3] + sy * M[4] + sz * M[5] + T[1];
  float oz = sx * M[6] + sy * M[7] + sz * M[8] + T[2];
  // SH lighting
  const float kc1 = 1.7724539f;             // a1*c1 = sqrt(pi)
  const float kc2 = 2.4270324f;             // a2*c2
  const float kd0 = 0.28867513f;            // 0.5/sqrt(3)
  float Y[9];
  Y[0] = 0.8862269f;                        // a0*c0
  Y[1] = -kc1 * ny;
  Y[2] = kc1 * nz;
  Y[3] = -kc1 * nx;
  Y[4] = kc2 * nx * ny;
  Y[5] = -kc2 * ny * nz;
  Y[6] = kc2 * kd0 * (3.f * nz * nz - 1.f);
  Y[7] = -kc2 * nx * nz;
  Y[8] = kc2 * 0.5f * (nx * nx - ny * ny);
  const float* g = G + b * 27;
  const u16* tp = texb + (size_t)b * NV3 + (size_t)v * 3;
  size_t ofc = (size_t)b * NV3 + (size_t)v * 3;
#pragma unroll
  for (int d = 0; d < 3; d++) {
    float L = 0.f;
#pragma unroll
    for (int cc = 0; cc < 9; cc++) L += Y[cc] * g[cc * 3 + d];
    out[ofc + d] = b2f(tp[d]) * L;
  }
  out[ST_BASE + ofc + 0] = ox;
  out[ST_BASE + ofc + 1] = oy;
  out[ST_BASE + ofc + 2] = oz;
}

// K5: landmarks — recompute shape_t at 68 kp verts, project (f32 out).
__global__ __launch_bounds__(128) void k_lms(const float* __restrict__ shp, const int* __restrict__ kp,
                                             const float* __restrict__ rot, const float* __restrict__ tr,
                                             float* __restrict__ out) {
  int t = threadIdx.x;
  int b = blockIdx.x;
  if (t >= 68) return;
  int v = kp[t];
  const float* sp = shp + (size_t)b * NV3 + (size_t)v * 3;
  float sx = sp[0], sy = sp[1], sz = sp[2];
  const float* M = rot + b * 9;
  const float* T = tr + b * 3;
  float ox = sx * M[0] + sy * M[1] + sz * M[2] + T[0];
  float oy = sx * M[3] + sy * M[4] + sz * M[5] + T[1];
  float oz = sx * M[6] + sy * M[7] + sz * M[8] + T[2];
  float w = 10.f - oz;                      // pts@[1,1,-1] + [0,0,10]
  float invw = 1.0f / w;
  float lx = 1015.f * ox * invw + 128.f;    // FOCAL*x/w + half
  float ly = 1015.f * oy * invw + 128.f;
  size_t o = LMS_BASE + ((size_t)b * 68 + t) * 2;
  out[o + 0] = lx;
  out[o + 1] = 256.f - ly;                  // IMG - y
}

extern "C" void kernel_launch(void* const* d_in, const int* in_sizes, int n_in,
                              void* d_out, int out_size, void* d_ws, size_t ws_size,
                              hipStream_t stream) {
  const float* coeff     = (const float*)d_in[0];
  const float* meanshape = (const float*)d_in[1];
  const float* idB       = (const float*)d_in[2];
  const float* exB       = (const float*)d_in[3];
  const float* meantex   = (const float*)d_in[4];
  const float* txB       = (const float*)d_in[5];
  const int* tri         = (const int*)d_in[6];
  const int* pbuf        = (const int*)d_in[7];
  const int* kp          = (const int*)d_in[8];
  float* out = (float*)d_out;
  char* ws = (char*)d_ws;
  float* shp  = (float*)(ws + SHAPE_OFF);
  u16* tex    = (u16*)(ws + TEX_OFF);
  u16* fnw    = (u16*)(ws + FN_OFF);
  u16* cpack  = (u16*)(ws + CPACK_OFF);
  float* rot  = (float*)(ws + ROT_OFF);
  float* G    = (float*)(ws + G_OFF);
  float* tr   = (float*)(ws + TRANS_OFF);
  float* mean = (float*)(ws + MEAN_OFF);

  k_mean<<<1, 256, 0, stream>>>(meanshape, mean);
  k_params<<<1, 128, 0, stream>>>(coeff, cpack, rot, G, tr);
  k_gemm<<<1674, 256, 0, stream>>>(idB, exB, txB, meanshape, meantex, cpack, mean, shp, tex);
  k_fn<<<dim3(277, 128), 256, 0, stream>>>(shp, tri, fnw);
  k_final<<<dim3(140, 128), 256, 0, stream>>>(shp, tex, fnw, pbuf, rot, G, tr, out);
  k_lms<<<128, 128, 0, stream>>>(shp, kp, rot, tr, out);
}

// Round 3
// 693.732 us; speedup vs baseline: 1.2419x; 1.2419x over previous
//
#include <hip/hip_runtime.h>

typedef unsigned short u16;
typedef __attribute__((ext_vector_type(8))) short bfrag;     // 8 bf16 (4 VGPRs) MFMA A/B
typedef __attribute__((ext_vector_type(4))) float ffrag;     // 4 f32 MFMA C/D
typedef __attribute__((ext_vector_type(4))) float f4;
typedef __attribute__((ext_vector_type(4))) int i4;
typedef __attribute__((ext_vector_type(4))) _Float16 h4;     // fn: xyz + pad, 8 B

#define NVERT 35709
#define NFACE 70789
#define NV3   107127
#define NB    128

// ---- workspace byte layout (total ~154.85 MB) ----
#define SHAPE_OFF 0ull            // f32, NB*NV3            (54,849,024 B)
#define TEX_OFF   54849024ull     // u16 bf16, NB*NV3       (27,424,512 B)
#define FN_OFF    82273536ull     // f16x4, NB*NFACE        (72,487,936 B)
#define CPACK_OFF 154761472ull    // u16 bf16, NB*256 padded coeffs [id80|0*16|ex64|tex80|0*16]
#define ROT_OFF   154827008ull    // f32, NB*9  (M[d][c], M = Rz@Ry@Rx)
#define G_OFF     154831616ull    // f32, NB*27 (G[c][d] = gamma[d*9+c] + 0.8*(c==0))
#define TRANS_OFF 154845440ull    // f32, NB*3
#define MEAN_OFF  154846976ull    // f32, 3
#define PART_OFF  154847040ull    // f32, 64*3 partial sums for mean

// ---- output element offsets (f32 out) ----
#define LMS_BASE  13712256ull     // after face_color (B*NV*3)
#define ST_BASE   13729664ull     // after lms (B*68*2)

__device__ __forceinline__ float b2f(u16 s) {
  union { unsigned u; float f; } v; v.u = ((unsigned)s) << 16; return v.f;
}
__device__ __forceinline__ u16 f2b(float x) {  // f32 -> bf16 RNE
  union { float f; unsigned u; } v; v.f = x;
  unsigned r = v.u + 0x7FFFu + ((v.u >> 16) & 1u);
  return (u16)(r >> 16);
}
__device__ __forceinline__ bfrag cvt8nt(const float* p) {  // 8 f32 (nt) -> 8 bf16
  f4 a = __builtin_nontemporal_load((const f4*)p);
  f4 b = __builtin_nontemporal_load((const f4*)(p + 4));
  bfrag r;
  r[0] = (short)f2b(a.x); r[1] = (short)f2b(a.y); r[2] = (short)f2b(a.z); r[3] = (short)f2b(a.w);
  r[4] = (short)f2b(b.x); r[5] = (short)f2b(b.y); r[6] = (short)f2b(b.z); r[7] = (short)f2b(b.w);
  return r;
}

// K0: partial sums of meanshape over vertices (64 blocks x 3 comps)
__global__ __launch_bounds__(256) void k_mean(const float* __restrict__ ms, float* __restrict__ part) {
  __shared__ float s[3];
  if (threadIdx.x < 3) s[threadIdx.x] = 0.f;
  __syncthreads();
  float a0 = 0.f, a1 = 0.f, a2 = 0.f;
  for (int v = blockIdx.x * 256 + threadIdx.x; v < NVERT; v += 64 * 256) {
    a0 += ms[v * 3 + 0];
    a1 += ms[v * 3 + 1];
    a2 += ms[v * 3 + 2];
  }
  atomicAdd(&s[0], a0); atomicAdd(&s[1], a1); atomicAdd(&s[2], a2);
  __syncthreads();
  if (threadIdx.x < 3) part[blockIdx.x * 3 + threadIdx.x] = s[threadIdx.x];
}

// K1: finalize mean; per-batch params: bf16-packed coeffs, rotation M = Rz@Ry@Rx (M[d][c]),
//     G[c][d] (gamma transposed, +0.8 on c==0), trans.
__global__ __launch_bounds__(128) void k_params(const float* __restrict__ coeff, u16* __restrict__ cpack,
                                                float* __restrict__ rot, float* __restrict__ G,
                                                float* __restrict__ tr, const float* __restrict__ part,
                                                float* __restrict__ mean) {
  int b = threadIdx.x;
  if (b < 3) {
    float s = 0.f;
    for (int i = 0; i < 64; i++) s += part[i * 3 + b];
    mean[b] = s * (1.0f / (float)NVERT);
  }
  const float* c = coeff + b * 257;
  u16* cp = cpack + b * 256;
  for (int k = 0; k < 80; k++) cp[k] = f2b(c[k]);            // id
  for (int k = 80; k < 96; k++) cp[k] = 0;                   // pad
  for (int k = 0; k < 64; k++) cp[96 + k] = f2b(c[80 + k]);  // ex
  for (int k = 0; k < 80; k++) cp[160 + k] = f2b(c[144 + k]);// tex
  for (int k = 240; k < 256; k++) cp[k] = 0;                 // pad
  float ax = c[224], ay = c[225], az = c[226];
  float sx = sinf(ax), cx = cosf(ax);
  float sy = sinf(ay), cy = cosf(ay);
  float sz = sinf(az), cz = cosf(az);
  float* M = rot + b * 9;
  M[0] = cz * cy;  M[1] = cz * sy * sx - sz * cx;  M[2] = sz * sx + cz * sy * cx;
  M[3] = sz * cy;  M[4] = cz * cx + sz * sy * sx;  M[5] = sz * sy * cx - cz * sx;
  M[6] = -sy;      M[7] = cy * sx;                 M[8] = cy * cx;
  float* g = G + b * 27;
  for (int cc = 0; cc < 9; cc++)
    for (int d = 0; d < 3; d++)
      g[cc * 3 + d] = c[227 + d * 9 + cc] + (cc == 0 ? 0.8f : 0.0f);
  float* t = tr + b * 3;
  t[0] = c[254]; t[1] = c[255]; t[2] = c[256];
}

// K2: MFMA GEMM, f32 bases nt-loaded, converted to bf16 in-register.
// D[b][j] = sum_k coeff[b][k]*base[j][k]. Each wave owns one 16-wide j tile, loads B frags
// once, loops all 8 batch tiles of 16.
__global__ __launch_bounds__(256) void k_gemm(const float* __restrict__ idB, const float* __restrict__ exB,
                                              const float* __restrict__ txB, const float* __restrict__ ms,
                                              const float* __restrict__ mt, const u16* __restrict__ cpack,
                                              const float* __restrict__ meanc,
                                              float* __restrict__ shp, u16* __restrict__ texo) {
  int wave = threadIdx.x >> 6, lane = threadIdx.x & 63;
  int jt = blockIdx.x * 4 + wave;
  int col = lane & 15, quad = lane >> 4;
  int j = jt * 16 + col;
  bool jv = (j < NV3);
  int jc = jv ? j : (NV3 - 1);                 // clamped: loads always in-bounds
  bfrag z8 = {0, 0, 0, 0, 0, 0, 0, 0};
  bfrag bid[3], bex[2], btx[3];
  const float* rowI = idB + (size_t)jc * 80;
  const float* rowT = txB + (size_t)jc * 80;
  const float* rowE = exB + (size_t)jc * 64;
#pragma unroll
  for (int f = 0; f < 3; f++) {
    int k = f * 32 + quad * 8;
    bool ok = (k < 80);
    int ks = ok ? k : 0;                       // clamped address, select value
    bfrag vi = cvt8nt(rowI + ks);
    bfrag vt = cvt8nt(rowT + ks);
    bid[f] = ok ? vi : z8;
    btx[f] = ok ? vt : z8;
  }
#pragma unroll
  for (int f = 0; f < 2; f++) {
    int k = f * 32 + quad * 8;                 // <= 56, always in-bounds
    bex[f] = cvt8nt(rowE + k);
  }
  float msj = ms[jc];
  float mtj = mt[jc];
  float mc = meanc[jc % 3];

  for (int bt = 0; bt < 8; bt++) {
    const u16* cp = cpack + (size_t)(bt * 16 + col) * 256;  // A: m=lane&15, k=quad*8+i
    ffrag accS = {0.f, 0.f, 0.f, 0.f};
    ffrag accT = {0.f, 0.f, 0.f, 0.f};
#pragma unroll
    for (int f = 0; f < 3; f++) {
      bfrag a = *(const bfrag*)(cp + f * 32 + quad * 8);
      accS = __builtin_amdgcn_mfma_f32_16x16x32_bf16(a, bid[f], accS, 0, 0, 0);
    }
#pragma unroll
    for (int f = 0; f < 2; f++) {
      bfrag a = *(const bfrag*)(cp + 96 + f * 32 + quad * 8);
      accS = __builtin_amdgcn_mfma_f32_16x16x32_bf16(a, bex[f], accS, 0, 0, 0);
    }
#pragma unroll
    for (int f = 0; f < 3; f++) {
      bfrag a = *(const bfrag*)(cp + 160 + f * 32 + quad * 8);
      accT = __builtin_amdgcn_mfma_f32_16x16x32_bf16(a, btx[f], accT, 0, 0, 0);
    }
    if (jv) {
#pragma unroll
      for (int r = 0; r < 4; r++) {
        int br = bt * 16 + quad * 4 + r;       // C/D: col=lane&15, row=quad*4+reg
        size_t o = (size_t)br * NV3 + j;
        __builtin_nontemporal_store(accS[r] + msj - mc, shp + o);
        __builtin_nontemporal_store(f2b(accT[r] + mtj), texo + o);
      }
    }
  }
}

// K3: face normals fn = cross(v1-v2, v2-v3), stored f16 xyz+pad (8B aligned), nt write.
// XCD batch-affinity swizzle: xcd = g&7, b = batch_idx*8 + xcd -> per-XCD shp gather set stays
// L2-resident (~0.43 MB/batch).
#define FN_CH 277
__global__ __launch_bounds__(256) void k_fn(const float* __restrict__ shp, const int* __restrict__ tri,
                                            h4* __restrict__ fnw) {
  int g = blockIdx.x;
  int xcd = g & 7, s = g >> 3;
  int b = (s / FN_CH) * 8 + xcd;
  int f = (s % FN_CH) * 256 + threadIdx.x;
  if (f >= NFACE) return;
  int i0 = tri[f * 3 + 0] - 1, i1 = tri[f * 3 + 1] - 1, i2 = tri[f * 3 + 2] - 1;
  const float* sv = shp + (size_t)b * NV3;
  float x1 = sv[i0 * 3], y1 = sv[i0 * 3 + 1], z1 = sv[i0 * 3 + 2];
  float x2 = sv[i1 * 3], y2 = sv[i1 * 3 + 1], z2 = sv[i1 * 3 + 2];
  float x3 = sv[i2 * 3], y3 = sv[i2 * 3 + 1], z3 = sv[i2 * 3 + 2];
  float e1x = x1 - x2, e1y = y1 - y2, e1z = z1 - z2;
  float e2x = x2 - x3, e2y = y2 - y3, e2z = z2 - z3;
  h4 st;
  st.x = (_Float16)(e1y * e2z - e1z * e2y);
  st.y = (_Float16)(e1z * e2x - e1x * e2z);
  st.z = (_Float16)(e1x * e2y - e1y * e2x);
  st.w = (_Float16)0.f;
  __builtin_nontemporal_store(st, fnw + (size_t)b * NFACE + f);
}

// K4: vn = sum of 8 gathered fn (index NFACE -> zero row), normalize, rotate; illuminate tex;
//     write face_color and shape_t (f32 out). Same XCD batch-affinity swizzle; fn gathers are
//     normal (cached) loads, all streaming traffic is nt.
#define FI_CH 140
__global__ __launch_bounds__(256) void k_final(const float* __restrict__ shp, const u16* __restrict__ texb,
                                               const h4* __restrict__ fnw, const int* __restrict__ pbuf,
                                               const float* __restrict__ rot, const float* __restrict__ G,
                                               const float* __restrict__ tr, float* __restrict__ out) {
  int g = blockIdx.x;
  int xcd = g & 7, s = g >> 3;
  int b = (s / FI_CH) * 8 + xcd;
  int v = (s % FI_CH) * 256 + threadIdx.x;
  if (v >= NVERT) return;
  i4 p0 = *(const i4*)(pbuf + (size_t)v * 8);
  i4 p1 = *(const i4*)(pbuf + (size_t)v * 8 + 4);
  int idx[8] = {p0.x, p0.y, p0.z, p0.w, p1.x, p1.y, p1.z, p1.w};
  float vx = 0.f, vy = 0.f, vz = 0.f;
  const h4* fb = fnw + (size_t)b * NFACE;
#pragma unroll
  for (int i = 0; i < 8; i++) {
    int id = idx[i] - 1;               // in [0, NFACE]; NFACE == appended zero row
    if (id < NFACE) {
      h4 q = fb[id];
      vx += (float)q.x; vy += (float)q.y; vz += (float)q.z;
    }
  }
  float n2 = vx * vx + vy * vy + vz * vz;
  float inv = rsqrtf(fmaxf(n2, 1e-30f));
  vx *= inv; vy *= inv; vz *= inv;
  const float* M = rot + b * 9;
  float nx = vx * M[0] + vy * M[1] + vz * M[2];
  float ny = vx * M[3] + vy * M[4] + vz * M[5];
  float nz = vx * M[6] + vy * M[7] + vz * M[8];
  const float* sp = shp + (size_t)b * NV3 + (size_t)v * 3;
  float sx = __builtin_nontemporal_load(sp);
  float sy = __builtin_nontemporal_load(sp + 1);
  float sz = __builtin_nontemporal_load(sp + 2);
  const float* T = tr + b * 3;
  float ox = sx * M[0] + sy * M[1] + sz * M[2] + T[0];
  float oy = sx * M[3] + sy * M[4] + sz * M[5] + T[1];
  float oz = sx * M[6] + sy * M[7] + sz * M[8] + T[2];
  // SH lighting
  const float kc1 = 1.7724539f;             // a1*c1 = sqrt(pi)
  const float kc2 = 2.4270324f;             // a2*c2
  const float kd0 = 0.28867513f;            // 0.5/sqrt(3)
  float Y[9];
  Y[0] = 0.8862269f;                        // a0*c0
  Y[1] = -kc1 * ny;
  Y[2] = kc1 * nz;
  Y[3] = -kc1 * nx;
  Y[4] = kc2 * nx * ny;
  Y[5] = -kc2 * ny * nz;
  Y[6] = kc2 * kd0 * (3.f * nz * nz - 1.f);
  Y[7] = -kc2 * nx * nz;
  Y[8] = kc2 * 0.5f * (nx * nx - ny * ny);
  const float* gg = G + b * 27;
  const u16* tp = texb + (size_t)b * NV3 + (size_t)v * 3;
  size_t ofc = (size_t)b * NV3 + (size_t)v * 3;
#pragma unroll
  for (int d = 0; d < 3; d++) {
    float L = 0.f;
#pragma unroll
    for (int cc = 0; cc < 9; cc++) L += Y[cc] * gg[cc * 3 + d];
    float t = b2f(__builtin_nontemporal_load(tp + d));
    __builtin_nontemporal_store(t * L, out + ofc + d);
  }
  __builtin_nontemporal_store(ox, out + ST_BASE + ofc + 0);
  __builtin_nontemporal_store(oy, out + ST_BASE + ofc + 1);
  __builtin_nontemporal_store(oz, out + ST_BASE + ofc + 2);
}

// K5: landmarks — recompute shape_t at 68 kp verts, project (f32 out).
__global__ __launch_bounds__(128) void k_lms(const float* __restrict__ shp, const int* __restrict__ kp,
                                             const float* __restrict__ rot, const float* __restrict__ tr,
                                             float* __restrict__ out) {
  int t = threadIdx.x;
  int b = blockIdx.x;
  if (t >= 68) return;
  int v = kp[t];
  const float* sp = shp + (size_t)b * NV3 + (size_t)v * 3;
  float sx = sp[0], sy = sp[1], sz = sp[2];
  const float* M = rot + b * 9;
  const float* T = tr + b * 3;
  float ox = sx * M[0] + sy * M[1] + sz * M[2] + T[0];
  float oy = sx * M[3] + sy * M[4] + sz * M[5] + T[1];
  float oz = sx * M[6] + sy * M[7] + sz * M[8] + T[2];
  float w = 10.f - oz;                      // pts@[1,1,-1] + [0,0,10]
  float invw = 1.0f / w;
  float lx = 1015.f * ox * invw + 128.f;    // FOCAL*x/w + half
  float ly = 1015.f * oy * invw + 128.f;
  size_t o = LMS_BASE + ((size_t)b * 68 + t) * 2;
  out[o + 0] = lx;
  out[o + 1] = 256.f - ly;                  // IMG - y
}

extern "C" void kernel_launch(void* const* d_in, const int* in_sizes, int n_in,
                              void* d_out, int out_size, void* d_ws, size_t ws_size,
                              hipStream_t stream) {
  const float* coeff     = (const float*)d_in[0];
  const float* meanshape = (const float*)d_in[1];
  const float* idB       = (const float*)d_in[2];
  const float* exB       = (const float*)d_in[3];
  const float* meantex   = (const float*)d_in[4];
  const float* txB       = (const float*)d_in[5];
  const int* tri         = (const int*)d_in[6];
  const int* pbuf        = (const int*)d_in[7];
  const int* kp          = (const int*)d_in[8];
  float* out = (float*)d_out;
  char* ws = (char*)d_ws;
  float* shp  = (float*)(ws + SHAPE_OFF);
  u16* tex    = (u16*)(ws + TEX_OFF);
  h4* fnw     = (h4*)(ws + FN_OFF);
  u16* cpack  = (u16*)(ws + CPACK_OFF);
  float* rot  = (float*)(ws + ROT_OFF);
  float* G    = (float*)(ws + G_OFF);
  float* tr   = (float*)(ws + TRANS_OFF);
  float* mean = (float*)(ws + MEAN_OFF);
  float* part = (float*)(ws + PART_OFF);

  k_mean<<<64, 256, 0, stream>>>(meanshape, part);
  k_params<<<1, 128, 0, stream>>>(coeff, cpack, rot, G, tr, part, mean);
  k_gemm<<<1674, 256, 0, stream>>>(idB, exB, txB, meanshape, meantex, cpack, mean, shp, tex);
  k_fn<<<8 * 16 * FN_CH, 256, 0, stream>>>(shp, tri, fnw);
  k_final<<<8 * 16 * FI_CH, 256, 0, stream>>>(shp, tex, fnw, pbuf, rot, G, tr, out);
  k_lms<<<128, 128, 0, stream>>>(shp, kp, rot, tr, out);
}